// Round 1
// baseline (599.261 us; speedup 1.0000x reference)
//
#include <hip/hip_runtime.h>
#include <hip/hip_bf16.h>

// ---------------------------------------------------------------------------
// GRACE contrastive loss, MI355X.
//  out = mean_k 0.5*(log d1_k + log d2_k) - s12[k,k]/tau
//  d1_k = sum_j exp(s11/t) + sum_j exp(s12/t) - exp(s11_kk/t)
//  d2_k = sum_j exp(s22/t) + sum_j exp(s21/t) - exp(s22_kk/t)
// With M=[n1;n2] (24576x256) everything is row sums of exp(M M^T / tau)
// split by j-half, plus diagonal probes.
// ---------------------------------------------------------------------------

#define NROWS 12288
#define TWO_N 24576
#define KDIM 256
#define BM 128
#define BN 128
#define BK 32
#define NCHUNK 4
#define JCHUNK (TWO_N / NCHUNK) /* 6144 */
#define LOG2E 1.4426950408889634f
#define TWOLOG2E 2.8853900817779268f /* (1/tau)*log2(e), tau=0.5 */

#if __has_builtin(__builtin_amdgcn_exp2f)
#define EXP2F(x) __builtin_amdgcn_exp2f(x)
#else
#define EXP2F(x) exp2f(x)
#endif

typedef __bf16 bf16x8 __attribute__((ext_vector_type(8)));
typedef __bf16 bf16x4v __attribute__((ext_vector_type(4)));
typedef float f32x4 __attribute__((ext_vector_type(4)));

typedef const __attribute__((address_space(1))) void* gptr_t;
typedef __attribute__((address_space(3))) void* lptr_t;

// ---- stage one 128x32 bf16 slab (8KB) into LDS, XOR-swizzled -------------
// LDS layout: row r at r*64B, 4 16B-blocks; LDS block c holds global k-block
// (c ^ (r&3)).  Swizzle is applied on the GLOBAL source address so it stays
// compatible with global_load_lds's wave-uniform-base + lane*16 destination.
// Fragment reads then hit 8 distinct 4-bank groups uniformly (conflict-free).
__device__ __forceinline__ void stage_slab(const __bf16* g, int row0, int kelem,
                                           __bf16* lds, int w, int l) {
#pragma unroll
  for (int t = 0; t < 2; ++t) {
    int chunk = w * 2 + t;          // 0..7, each 1KB = 16 rows
    int r = chunk * 16 + (l >> 2);  // local row 0..127
    int c = l & 3;                  // 16B block slot within row
    int src = c ^ (r & 3);          // global k-block that lands in slot c
    const __bf16* ga = g + (size_t)(row0 + r) * KDIM + kelem + src * 8;
    __bf16* la = lds + chunk * 512; // wave-uniform base (512 elems = 1KB)
    __builtin_amdgcn_global_load_lds((gptr_t)ga, (lptr_t)la, 16, 0, 0);
  }
}

// A/B fragment for 16x16x32 bf16: lane holds row (l&15), k = (l>>4)*8 + j.
__device__ __forceinline__ bf16x8 read_frag(const __bf16* lds, int rowbase,
                                            int tile, int l) {
  int r = rowbase + tile * 16 + (l & 15);
  int q = l >> 4;
  int blk = q ^ (r & 3);            // undo swizzle
  return *(const bf16x8*)(lds + r * 32 + blk * 8);
}

// ---- 128x128 output tile, K=256, acc[mi][ni] per wave (2x2 wave grid) ----
__device__ __forceinline__ void gemm_tile_core(const __bf16* A, int arow0,
                                               const __bf16* B, int brow0,
                                               __bf16* As, __bf16* Bs,
                                               f32x4 (&acc)[4][4], int w, int l) {
  const int warow = (w >> 1) * 64;
  const int wbrow = (w & 1) * 64;
#pragma unroll
  for (int ks = 0; ks < KDIM / BK; ++ks) {
    __syncthreads();                       // protect LDS from prior readers
    stage_slab(A, arow0, ks * BK, As, w, l);
    stage_slab(B, brow0, ks * BK, Bs, w, l);
    __syncthreads();                       // compiler drains vmcnt here
    bf16x8 aF[4], bF[4];
#pragma unroll
    for (int mi = 0; mi < 4; ++mi) aF[mi] = read_frag(As, warow, mi, l);
#pragma unroll
    for (int ni = 0; ni < 4; ++ni) bF[ni] = read_frag(Bs, wbrow, ni, l);
#pragma unroll
    for (int mi = 0; mi < 4; ++mi)
#pragma unroll
      for (int ni = 0; ni < 4; ++ni)
        acc[mi][ni] = __builtin_amdgcn_mfma_f32_16x16x32_bf16(
            aF[mi], bF[ni], acc[mi][ni], 0, 0, 0);
  }
}

// ---------------------------------------------------------------------------
__global__ void cast_kernel(const float* __restrict__ src,
                            __bf16* __restrict__ dst, int n4) {
  int i = blockIdx.x * blockDim.x + threadIdx.x;
  if (i >= n4) return;
  float4 v = *(const float4*)(src + (size_t)i * 4);
  bf16x4v o;
  o[0] = (__bf16)v.x; o[1] = (__bf16)v.y; o[2] = (__bf16)v.z; o[3] = (__bf16)v.w;
  *(bf16x4v*)(dst + (size_t)i * 4) = o;
}

// T = ELU(Z @ W1^T + b1), stored bf16
__global__ __launch_bounds__(256, 2) void proj1_kernel(
    const __bf16* __restrict__ Zb, const __bf16* __restrict__ W1b,
    const float* __restrict__ b1, __bf16* __restrict__ Tb) {
  __shared__ __align__(16) __bf16 As[BM * BK];
  __shared__ __align__(16) __bf16 Bs[BN * BK];
  int w = threadIdx.x >> 6, l = threadIdx.x & 63;
  int i0 = blockIdx.x * BM, j0 = blockIdx.y * BN;
  int warow = (w >> 1) * 64, wbrow = (w & 1) * 64;
  f32x4 acc[4][4] = {};
  gemm_tile_core(Zb, i0, W1b, j0, As, Bs, acc, w, l);
  float bias[4];
#pragma unroll
  for (int ni = 0; ni < 4; ++ni) bias[ni] = b1[j0 + wbrow + ni * 16 + (l & 15)];
#pragma unroll
  for (int mi = 0; mi < 4; ++mi)
#pragma unroll
    for (int ni = 0; ni < 4; ++ni)
#pragma unroll
      for (int v = 0; v < 4; ++v) {
        int row = i0 + warow + mi * 16 + (l >> 4) * 4 + v;
        int col = j0 + wbrow + ni * 16 + (l & 15);
        float x = acc[mi][ni][v] + bias[ni];
        x = x > 0.f ? x : (EXP2F(x * LOG2E) - 1.f);  // ELU
        Tb[(size_t)row * KDIM + col] = (__bf16)x;
      }
}

// H = T @ W2^T + b2 (fp32), plus per-row sum of squares via atomics
__global__ __launch_bounds__(256, 2) void proj2_kernel(
    const __bf16* __restrict__ Tb, const __bf16* __restrict__ W2b,
    const float* __restrict__ b2, float* __restrict__ H,
    float* __restrict__ SS) {
  __shared__ __align__(16) __bf16 As[BM * BK];
  __shared__ __align__(16) __bf16 Bs[BN * BK];
  int w = threadIdx.x >> 6, l = threadIdx.x & 63;
  int i0 = blockIdx.x * BM, j0 = blockIdx.y * BN;
  int warow = (w >> 1) * 64, wbrow = (w & 1) * 64;
  f32x4 acc[4][4] = {};
  gemm_tile_core(Tb, i0, W2b, j0, As, Bs, acc, w, l);
  float bias[4];
#pragma unroll
  for (int ni = 0; ni < 4; ++ni) bias[ni] = b2[j0 + wbrow + ni * 16 + (l & 15)];
  float ss[4][4] = {};
#pragma unroll
  for (int mi = 0; mi < 4; ++mi)
#pragma unroll
    for (int ni = 0; ni < 4; ++ni)
#pragma unroll
      for (int v = 0; v < 4; ++v) {
        int row = i0 + warow + mi * 16 + (l >> 4) * 4 + v;
        int col = j0 + wbrow + ni * 16 + (l & 15);
        float x = acc[mi][ni][v] + bias[ni];
        H[(size_t)row * KDIM + col] = x;
        ss[mi][v] += x * x;
      }
#pragma unroll
  for (int mi = 0; mi < 4; ++mi)
#pragma unroll
    for (int v = 0; v < 4; ++v) {
      float x = ss[mi][v];
      x += __shfl_xor(x, 1, 64);
      x += __shfl_xor(x, 2, 64);
      x += __shfl_xor(x, 4, 64);
      x += __shfl_xor(x, 8, 64);
      if ((l & 15) == 0)
        atomicAdd(&SS[i0 + warow + mi * 16 + (l >> 4) * 4 + v], x);
    }
}

// Nb = H * rsqrt(SS[row]), bf16
__global__ void norm_kernel(const float* __restrict__ H,
                            const float* __restrict__ SS,
                            __bf16* __restrict__ Nb) {
  int i = blockIdx.x * blockDim.x + threadIdx.x;
  size_t idx = (size_t)i * 4;
  if (idx >= (size_t)TWO_N * KDIM) return;
  int row = (int)(idx >> 8);
  float inv = rsqrtf(SS[row]);
  float4 h = *(const float4*)(H + idx);
  bf16x4v o;
  o[0] = (__bf16)(h.x * inv); o[1] = (__bf16)(h.y * inv);
  o[2] = (__bf16)(h.z * inv); o[3] = (__bf16)(h.w * inv);
  *(bf16x4v*)(Nb + idx) = o;
}

// Big kernel: row sums of exp(Nb Nb^T / tau), split by j-half; diag probes.
__global__ __launch_bounds__(256, 2) void sim_kernel(
    const __bf16* __restrict__ Nb, float* __restrict__ Rlow,
    float* __restrict__ Rhigh, float* __restrict__ Dsame,
    float* __restrict__ Dcross) {
  __shared__ __align__(16) __bf16 As[BM * BK];
  __shared__ __align__(16) __bf16 Bs[BN * BK];
  int w = threadIdx.x >> 6, l = threadIdx.x & 63;
  int i0 = blockIdx.x * BM;
  int chunk = blockIdx.y;
  int jbase = chunk * JCHUNK;
  int warow = (w >> 1) * 64, wbrow = (w & 1) * 64;
  float rs[4][4] = {};  // per-(mi,v) running row sums, persist across j loop

  for (int jt = 0; jt < JCHUNK / BN; ++jt) {
    int j0 = jbase + jt * BN;
    f32x4 acc[4][4] = {};
    gemm_tile_core(Nb, i0, Nb, j0, As, Bs, acc, w, l);
    bool dsame = (j0 == i0);
    bool dcross = (j0 == i0 + NROWS);
#pragma unroll
    for (int mi = 0; mi < 4; ++mi)
#pragma unroll
      for (int ni = 0; ni < 4; ++ni)
#pragma unroll
        for (int v = 0; v < 4; ++v) {
          float s = acc[mi][ni][v];             // cosine (rows pre-normalized)
          rs[mi][v] += EXP2F(s * TWOLOG2E);     // exp(s/tau)
          if (dsame | dcross) {
            int li = warow + mi * 16 + (l >> 4) * 4 + v;
            int lj = wbrow + ni * 16 + (l & 15);
            if (li == lj) {
              if (dsame) Dsame[i0 + li] = s;
              else       Dcross[i0 + li] = s;
            }
          }
        }
  }
  // cross-lane (16-wide) reduce, one atomicAdd per row per wave
  float* R = (chunk >= NCHUNK / 2) ? Rhigh : Rlow;
#pragma unroll
  for (int mi = 0; mi < 4; ++mi)
#pragma unroll
    for (int v = 0; v < 4; ++v) {
      float x = rs[mi][v];
      x += __shfl_xor(x, 1, 64);
      x += __shfl_xor(x, 2, 64);
      x += __shfl_xor(x, 4, 64);
      x += __shfl_xor(x, 8, 64);
      if ((l & 15) == 0)
        atomicAdd(&R[i0 + warow + mi * 16 + (l >> 4) * 4 + v], x);
    }
}

__global__ void finalize_kernel(const float* __restrict__ Rlow,
                                const float* __restrict__ Rhigh,
                                const float* __restrict__ Dsame,
                                const float* __restrict__ Dcross,
                                float* __restrict__ out) {
  __shared__ float red[256];
  float acc = 0.f;
  for (int k = threadIdx.x; k < NROWS; k += 256) {
    float d1 = Rlow[k] + Rhigh[k] - EXP2F(Dsame[k] * TWOLOG2E);
    float d2 = Rhigh[NROWS + k] + Rlow[NROWS + k] -
               EXP2F(Dsame[NROWS + k] * TWOLOG2E);
    acc += 0.5f * (logf(d1) + logf(d2)) - 2.f * Dcross[k];
  }
  red[threadIdx.x] = acc;
  __syncthreads();
  for (int s = 128; s > 0; s >>= 1) {
    if (threadIdx.x < s) red[threadIdx.x] += red[threadIdx.x + s];
    __syncthreads();
  }
  if (threadIdx.x == 0) out[0] = red[0] / (float)NROWS;
}

// ---------------------------------------------------------------------------
extern "C" void kernel_launch(void* const* d_in, const int* in_sizes, int n_in,
                              void* d_out, int out_size, void* d_ws,
                              size_t ws_size, hipStream_t stream) {
  const float* z1 = (const float*)d_in[0];
  const float* z2 = (const float*)d_in[1];
  const float* W1 = (const float*)d_in[2];
  const float* b1 = (const float*)d_in[3];
  const float* W2 = (const float*)d_in[4];
  const float* b2 = (const float*)d_in[5];
  float* out = (float*)d_out;

  char* ws = (char*)d_ws;
  size_t off = 0;
  auto alloc = [&](size_t bytes) -> void* {
    void* p = ws + off;
    off += (bytes + 255) & ~(size_t)255;
    return p;
  };
  __bf16* Zb   = (__bf16*)alloc((size_t)TWO_N * KDIM * 2); // reused as Nb
  __bf16* W1b  = (__bf16*)alloc((size_t)KDIM * KDIM * 2);
  __bf16* W2b  = (__bf16*)alloc((size_t)KDIM * KDIM * 2);
  __bf16* Tb   = (__bf16*)alloc((size_t)TWO_N * KDIM * 2);
  float*  H    = (float*)alloc((size_t)TWO_N * KDIM * 4);
  float*  SS   = (float*)alloc((size_t)TWO_N * 4);
  float*  Rlow = (float*)alloc((size_t)TWO_N * 4);
  float*  Rhigh= (float*)alloc((size_t)TWO_N * 4);
  float*  Dsame= (float*)alloc((size_t)TWO_N * 4);
  float*  Dcross=(float*)alloc((size_t)NROWS * 4);
  __bf16* Nb = Zb;  // Zb dead after proj1

  hipMemsetAsync(SS, 0, (size_t)TWO_N * 4, stream);
  hipMemsetAsync(Rlow, 0, (size_t)TWO_N * 4, stream);
  hipMemsetAsync(Rhigh, 0, (size_t)TWO_N * 4, stream);

  int n4z = NROWS * KDIM / 4;   // 786432
  int n4w = KDIM * KDIM / 4;    // 16384
  cast_kernel<<<(n4z + 255) / 256, 256, 0, stream>>>(z1, Zb, n4z);
  cast_kernel<<<(n4z + 255) / 256, 256, 0, stream>>>(z2, Zb + (size_t)NROWS * KDIM, n4z);
  cast_kernel<<<(n4w + 255) / 256, 256, 0, stream>>>(W1, W1b, n4w);
  cast_kernel<<<(n4w + 255) / 256, 256, 0, stream>>>(W2, W2b, n4w);

  proj1_kernel<<<dim3(TWO_N / BM, KDIM / BN), 256, 0, stream>>>(Zb, W1b, b1, Tb);
  proj2_kernel<<<dim3(TWO_N / BM, KDIM / BN), 256, 0, stream>>>(Tb, W2b, b2, H, SS);

  int n4n = TWO_N * KDIM / 4;   // 1572864
  norm_kernel<<<(n4n + 255) / 256, 256, 0, stream>>>(H, SS, Nb);

  sim_kernel<<<dim3(TWO_N / BM, NCHUNK), 256, 0, stream>>>(Nb, Rlow, Rhigh,
                                                           Dsame, Dcross);
  finalize_kernel<<<1, 256, 0, stream>>>(Rlow, Rhigh, Dsame, Dcross, out);
}